// Round 1
// baseline (428.631 us; speedup 1.0000x reference)
//
#include <hip/hip_runtime.h>

// inverse 2x2 wavelet-style recombination
// X: (16, 256, 128, 128) f32, channel layout ch = j*64 + cc, j in [0,4)
// O: (16, 64, 256, 256) f32, O[b,cc,2h+p,2w+q] = M1[2p+q] . (t0,t1,t2,t3)
// t0 = M2row0 . X[b, j*64+cc, h,      w    ]
// t1 = M2row1 . X[b, j*64+cc, h-1,    w    ]   (h wrap mod 128)
// t2 = M2row2 . X[b, j*64+cc, h,      w-1  ]   (w wrap mod 128)
// t3 = M2row3 . X[b, j*64+cc, h-1,    w-1  ]

__global__ __launch_bounds__(256) void inlwt_kernel(const float* __restrict__ x,
                                                    float* __restrict__ out) {
    // thread -> (b, cc, h, w4): w4 fastest (32), then h (128), cc (64), b (16)
    const int idx = blockIdx.x * 256 + threadIdx.x;
    const int w4 = idx & 31;
    const int h  = (idx >> 5) & 127;
    const int cc = (idx >> 12) & 63;
    const int b  = idx >> 18;

    const int w0 = w4 << 2;          // first of 4 w positions
    const int hm = (h - 1) & 127;    // wrapped h-1
    const int wl = (w0 - 1) & 127;   // wrapped w0-1

    // M2 = P2MULU2 rows, M1 = P1MULU1DIV4 rows
    const float M2[4][4] = {
        { 1.3968f, -0.2212f, -0.5412f,  1.3066f},
        { 0.2212f,  1.3968f, -1.3066f, -0.5412f},
        {-0.2212f, -1.3968f, -1.3066f, -0.5412f},
        {-1.3968f,  0.2212f, -0.5412f,  1.3066f}};
    const float M1[4][4] = {
        { 0.2166f, -0.0256f,  0.1213f,  0.0144f},
        { 0.0256f,  0.2166f,  0.0144f, -0.1213f},
        { 0.1213f, -0.0144f, -0.2166f, -0.0256f},
        {-0.0144f, -0.1213f,  0.0256f, -0.2166f}};

    float t0[4] = {0.f, 0.f, 0.f, 0.f};
    float t1[4] = {0.f, 0.f, 0.f, 0.f};
    float t2[4] = {0.f, 0.f, 0.f, 0.f};
    float t3[4] = {0.f, 0.f, 0.f, 0.f};

#pragma unroll
    for (int j = 0; j < 4; ++j) {
        const float* base = x + (((b * 256 + j * 64 + cc) * 128) << 7);
        const float4 vh = *reinterpret_cast<const float4*>(base + (h  << 7) + w0);
        const float4 vm = *reinterpret_cast<const float4*>(base + (hm << 7) + w0);
        const float  ah = base[(h  << 7) + wl];
        const float  am = base[(hm << 7) + wl];

        const float xh[4]  = {vh.x, vh.y, vh.z, vh.w};   // (h,   w)
        const float xm[4]  = {vm.x, vm.y, vm.z, vm.w};   // (h-1, w)
        const float xhl[4] = {ah,   vh.x, vh.y, vh.z};   // (h,   w-1)
        const float xml[4] = {am,   vm.x, vm.y, vm.z};   // (h-1, w-1)

#pragma unroll
        for (int l = 0; l < 4; ++l) {
            t0[l] = fmaf(M2[0][j], xh[l],  t0[l]);
            t1[l] = fmaf(M2[1][j], xm[l],  t1[l]);
            t2[l] = fmaf(M2[2][j], xhl[l], t2[l]);
            t3[l] = fmaf(M2[3][j], xml[l], t3[l]);
        }
    }

    float o[4][4];  // [i][l]
#pragma unroll
    for (int l = 0; l < 4; ++l) {
#pragma unroll
        for (int i = 0; i < 4; ++i) {
            o[i][l] = fmaf(M1[i][0], t0[l],
                      fmaf(M1[i][1], t1[l],
                      fmaf(M1[i][2], t2[l],
                           M1[i][3] * t3[l])));
        }
    }

    // output: row 2h gets (o0,o1) interleaved over q; row 2h+1 gets (o2,o3)
    float* orow0 = out + (((b * 64 + cc) * 256 + (h << 1)) << 8) + (w0 << 1);
    float* orow1 = orow0 + 256;

    float4 r0a = {o[0][0], o[1][0], o[0][1], o[1][1]};
    float4 r0b = {o[0][2], o[1][2], o[0][3], o[1][3]};
    float4 r1a = {o[2][0], o[3][0], o[2][1], o[3][1]};
    float4 r1b = {o[2][2], o[3][2], o[2][3], o[3][3]};

    *reinterpret_cast<float4*>(orow0)     = r0a;
    *reinterpret_cast<float4*>(orow0 + 4) = r0b;
    *reinterpret_cast<float4*>(orow1)     = r1a;
    *reinterpret_cast<float4*>(orow1 + 4) = r1b;
}

extern "C" void kernel_launch(void* const* d_in, const int* in_sizes, int n_in,
                              void* d_out, int out_size, void* d_ws, size_t ws_size,
                              hipStream_t stream) {
    const float* x = (const float*)d_in[0];
    float* o = (float*)d_out;
    // total threads = 16 * 64 * 128 * 32 = 4,194,304 -> 16384 blocks of 256
    inlwt_kernel<<<16384, 256, 0, stream>>>(x, o);
}